// Round 4
// baseline (272.277 us; speedup 1.0000x reference)
//
#include <hip/hip_runtime.h>
#include <math.h>

// Problem constants: B=8, S=128, V=32000, K=32.
constexpr int Bc = 8, Sc = 128, Vc = 32000, Kc = 32;
constexpr int ROWS = Bc * Sc;         // 1024
constexpr int V4 = Vc / 4;            // 8000 float4 per row
constexpr int CHUNKS = 4;             // chunks per row
constexpr int CHUNK_F4 = V4 / CHUNKS; // 2000 float4 per chunk
constexpr int NT = 256;               // threads per block (both kernels)

typedef float v4f __attribute__((ext_vector_type(4)));

// ---------------- Kernel A: per-(row,chunk) online-softmax partials ---------
// grid (ROWS, CHUNKS) x 256. Each block streams 32 KB of logit and writes a
// partial (m, s) pair to ws[ (row*CHUNKS + c)*2 .. +1 ].
__global__ __launch_bounds__(NT) void knn_reduce_kernel(
    const float* __restrict__ logit,
    float* __restrict__ ws)
{
    const int row = blockIdx.x;
    const int c   = blockIdx.y;
    const int t   = threadIdx.x;
    const v4f* __restrict__ x = (const v4f*)(logit + (size_t)row * Vc);
    const int begin = c * CHUNK_F4;
    const int end   = begin + CHUNK_F4;

    float m = -INFINITY, s = 0.f;
#pragma unroll 4
    for (int i = begin + t; i < end; i += NT) {
        const v4f v = x[i];
        const float m4 = fmaxf(fmaxf(v.x, v.y), fmaxf(v.z, v.w));
        const float mn = fmaxf(m, m4);
        s = s * __expf(m - mn)
          + __expf(v.x - mn) + __expf(v.y - mn)
          + __expf(v.z - mn) + __expf(v.w - mn);
        m = mn;
    }
    // wave-level (m,s) reduce
#pragma unroll
    for (int off = 32; off > 0; off >>= 1) {
        const float m2 = __shfl_xor(m, off);
        const float s2 = __shfl_xor(s, off);
        const float mn = fmaxf(m, m2);
        s = s * __expf(m - mn) + s2 * __expf(m2 - mn);
        m = mn;
    }
    __shared__ float rm[NT / 64], rs[NT / 64];
    const int wave = t >> 6;
    if ((t & 63) == 0) { rm[wave] = m; rs[wave] = s; }
    __syncthreads();
    if (t == 0) {
        float M = rm[0];
#pragma unroll
        for (int w = 1; w < NT / 64; ++w) M = fmaxf(M, rm[w]);
        float S = 0.f;
#pragma unroll
        for (int w = 0; w < NT / 64; ++w) S += rs[w] * __expf(rm[w] - M);
        const int slot = (row * CHUNKS + c) * 2;
        ws[slot]     = M;
        ws[slot + 1] = S;
    }
}

// ---------------- Kernel B: map + fused kNN scatter -------------------------
// grid (ROWS, CHUNKS) x 256. Combines the row's 4 partials, streams
// out = exp(x - M) * cn/Z over its own chunk, then lanes 0..63 apply the
// kNN scatter for targets falling inside THIS chunk's vocab range (so plain
// stores and atomics to the same address never cross block boundaries).
__global__ __launch_bounds__(NT) void knn_map_kernel(
    const float* __restrict__ logit,
    const float* __restrict__ ws,
    const int*   __restrict__ optor_vals,
    const float* __restrict__ optor_dists,
    const int*   __restrict__ const_vals,
    const float* __restrict__ const_dists,
    const int*   __restrict__ prev_words,
    const float* __restrict__ optor_lamda,
    const float* __restrict__ const_lamda,
    const float* __restrict__ optor_temp,
    const float* __restrict__ const_temp,
    float* __restrict__ out)
{
    const int row = blockIdx.x;
    const int c   = blockIdx.y;
    const int t   = threadIdx.x;

    // combine the 4 partials (uniform scalar work)
    const float* p = ws + row * CHUNKS * 2;
    float M = fmaxf(fmaxf(p[0], p[2]), fmaxf(p[4], p[6]));
    float Z = p[1] * __expf(p[0] - M) + p[3] * __expf(p[2] - M)
            + p[5] * __expf(p[4] - M) + p[7] * __expf(p[6] - M);

    const int pw = prev_words[row];
    const bool om = (pw <= 88) || (pw >= 91 && pw <= 291);
    const bool cm = (pw == 89) || (pw == 90) || (pw >= 292);
    const float omf = om ? 1.f : 0.f;
    const float cmf = cm ? 1.f : 0.f;
    const float ol = optor_lamda[0];
    const float cl = const_lamda[0];
    const float sc = ((1.f - ol) * omf + (1.f - cl) * cmf) / Z;

    const size_t base4 = (size_t)row * V4;
    const v4f* __restrict__ x = (const v4f*)logit + base4;
    v4f* __restrict__       o = (v4f*)out + base4;
    const int begin = c * CHUNK_F4;
    const int end   = begin + CHUNK_F4;
#pragma unroll 4
    for (int i = begin + t; i < end; i += NT) {
        v4f v = x[i];
        v.x = __expf(v.x - M) * sc;
        v.y = __expf(v.y - M) * sc;
        v.z = __expf(v.z - M) * sc;
        v.w = __expf(v.w - M) * sc;
        o[i] = v;
    }

    __syncthreads();   // drain this block's stores (vmcnt(0) before barrier)

    // kNN scatter for targets inside [begin*4, end*4): lanes 0..31 optor,
    // lanes 32..63 const. xor-shuffles with off<=16 stay within each half.
    if (t < 64) {
        const bool is_opt = (t < 32);
        const int k = t & 31;
        const float scale = is_opt ? ol * omf : cl * cmf;
        const int*   vals  = is_opt ? optor_vals  : const_vals;
        const float* dists = is_opt ? optor_dists : const_dists;
        const float  temp  = is_opt ? optor_temp[0] : const_temp[0];

        const float sv = -dists[row * Kc + k] / temp;
        float mx = sv;
#pragma unroll
        for (int off = 16; off > 0; off >>= 1)
            mx = fmaxf(mx, __shfl_xor(mx, off));
        const float e = __expf(sv - mx);
        float sm = e;
#pragma unroll
        for (int off = 16; off > 0; off >>= 1)
            sm += __shfl_xor(sm, off);
        const float w = e / sm;

        const int val = vals[row * Kc + k];
        if (scale != 0.f && val >= begin * 4 && val < end * 4)
            atomicAdd(out + (size_t)row * Vc + val, scale * w);
    }
}

extern "C" void kernel_launch(void* const* d_in, const int* in_sizes, int n_in,
                              void* d_out, int out_size, void* d_ws, size_t ws_size,
                              hipStream_t stream) {
    const float* logit       = (const float*)d_in[0];
    const int*   optor_vals  = (const int*)  d_in[1];
    const float* optor_dists = (const float*)d_in[2];
    const int*   const_vals  = (const int*)  d_in[3];
    const float* const_dists = (const float*)d_in[4];
    const int*   prev_words  = (const int*)  d_in[5];
    const float* optor_lamda = (const float*)d_in[6];
    const float* const_lamda = (const float*)d_in[7];
    const float* optor_temp  = (const float*)d_in[8];
    const float* const_temp  = (const float*)d_in[9];
    float* out = (float*)d_out;
    float* ws  = (float*)d_ws;   // ROWS*CHUNKS*2 floats = 32 KB

    knn_reduce_kernel<<<dim3(ROWS, CHUNKS), NT, 0, stream>>>(logit, ws);

    knn_map_kernel<<<dim3(ROWS, CHUNKS), NT, 0, stream>>>(
        logit, ws, optor_vals, optor_dists, const_vals, const_dists,
        prev_words, optor_lamda, const_lamda, optor_temp, const_temp, out);
}